// Round 7
// baseline (562.933 us; speedup 1.0000x reference)
//
#include <hip/hip_runtime.h>
#include <stdint.h>

#define NB 20
#define EG 16   // edges per wave in kB6

typedef __attribute__((ext_vector_type(8))) short bf16x8;
typedef __attribute__((ext_vector_type(4))) float f32x4;

__device__ __forceinline__ float bf_lo(uint32_t u) { return __uint_as_float(u << 16); }
__device__ __forceinline__ float bf_hi(uint32_t u) { return __uint_as_float(u & 0xffff0000u); }
__device__ __forceinline__ uint32_t f2bf(float f) {
    uint32_t u = __float_as_uint(f);
    return (u + 0x7fffu + ((u >> 16) & 1u)) >> 16;  // RNE
}
__device__ __forceinline__ uint32_t pack_bf2(float a, float b) {
    return f2bf(a) | (f2bf(b) << 16);
}
// fast silu: x * rcp(1 + 2^(-x*log2e))
__device__ __forceinline__ float silu_f(float x) {
    float e = __builtin_amdgcn_exp2f(-1.4426950408889634f * x);
    return x * __builtin_amdgcn_rcpf(1.f + e);
}

// ---------------------------------------------------------------------------
// prep: Mf32 = W2 @ Wu (fp32 [128][128]), cvec = b2 @ Wu (fp32). grid 129x64
// ---------------------------------------------------------------------------
__global__ void prep_kernel(const float* __restrict__ W2, const float* __restrict__ b2,
                            const float* __restrict__ Wu,
                            float* __restrict__ Mf32, float* __restrict__ cvec) {
    int q = threadIdx.x;           // cols 2q, 2q+1
    int k = blockIdx.x;            // 0..127 rows; 128 -> cvec
    const float* row = (k < 128) ? (W2 + k * 128) : b2;
    float acc0 = 0.f, acc1 = 0.f;
    for (int j = 0; j < 128; ++j) {
        float w = row[j];
        float2 wu = *(const float2*)(Wu + j * 128 + 2 * q);
        acc0 = fmaf(w, wu.x, acc0);
        acc1 = fmaf(w, wu.y, acc1);
    }
    if (k < 128) {
        Mf32[k * 128 + 2 * q] = acc0;
        Mf32[k * 128 + 2 * q + 1] = acc1;
    } else {
        cvec[2 * q] = acc0;
        cvec[2 * q + 1] = acc1;
    }
}

// ---------------------------------------------------------------------------
// prep2: W1[0:256] -> bf16 B-fragments for kA3. 16384 dwords.
// ---------------------------------------------------------------------------
__global__ void prep2(const float* __restrict__ W1, uint32_t* __restrict__ Bpk) {
    int d = blockIdx.x * 256 + threadIdx.x;   // 0..16383
    int q = d & 3, l = (d >> 2) & 63, c = (d >> 8) & 15, s = d >> 12;
    int k = 32 * s + ((l >> 4) << 3) + (q << 1);
    int col = (c << 4) + (l & 15);
    int r0 = (col < 128) ? k : (k + 128);
    int cc = col & 127;
    float v0 = W1[(size_t)r0 * 128 + cc];
    float v1 = W1[(size_t)(r0 + 1) * 128 + cc];
    Bpk[d] = pack_bf2(v0, v1);
}

// prepM: Mf32 -> bf16 B-fragments for kC2 (N=128: c 0..7). 8192 dwords.
__global__ void prepM(const float* __restrict__ Mf32, uint32_t* __restrict__ Mfrag) {
    int d = blockIdx.x * 256 + threadIdx.x;   // 0..8191
    int q = d & 3, l = (d >> 2) & 63, c = (d >> 8) & 7, s = d >> 11;
    int k = 32 * s + ((l >> 4) << 3) + (q << 1);
    int col = (c << 4) + (l & 15);
    Mfrag[d] = pack_bf2(Mf32[k * 128 + col], Mf32[(k + 1) * 128 + col]);
}

// ---------------------------------------------------------------------------
// kA3: MFMA GEMM P = edge_attr (E x 128) @ Bcat (128 x 256), bf16 out.
// ---------------------------------------------------------------------------
__global__ void __launch_bounds__(256) kA3(const float* __restrict__ edge_attr,
                                           const uint32_t* __restrict__ Bpk,
                                           uint16_t* __restrict__ Pb, int E) {
    __shared__ uint32_t As[4096];    // 64 rows x 64 dwords (16KB)
    __shared__ uint32_t Bs[16384];   // 64KB fragment-ordered B
    const int tid = threadIdx.x;
    const int e0 = blockIdx.x * 64;
    const int nE = min(64, E - e0);

    for (int d = tid; d < 4096; d += 256) {
        int row = d >> 6, p = d & 63;
        int g = p >> 2;
        float2 v;
        if (row < nE) v = *(const float2*)(edge_attr + (size_t)(e0 + row) * 128 + 2 * p);
        else { v.x = 0.f; v.y = 0.f; }
        As[row * 64 + ((g ^ (row & 7)) << 2) + (p & 3)] = pack_bf2(v.x, v.y);
    }
    for (int d = tid; d < 4096; d += 256)
        ((uint4*)Bs)[d] = ((const uint4*)Bpk)[d];
    __syncthreads();

    const int w = tid >> 6, l = tid & 63;

    bf16x8 afr[4][4];   // [rb][s]
#pragma unroll
    for (int rb = 0; rb < 4; ++rb)
#pragma unroll
        for (int s = 0; s < 4; ++s) {
            int row = rb * 16 + (l & 15);
            int g = s * 4 + (l >> 4);
            afr[rb][s] = *(const bf16x8*)((const char*)As + row * 256 + ((g ^ (row & 7)) << 4));
        }

    f32x4 acc[4][4];    // [cl][rb]
#pragma unroll
    for (int cl = 0; cl < 4; ++cl)
#pragma unroll
        for (int rb = 0; rb < 4; ++rb) acc[cl][rb] = (f32x4)(0.f);

#pragma unroll
    for (int cl = 0; cl < 4; ++cl) {
        const int c = w * 4 + cl;
#pragma unroll
        for (int s = 0; s < 4; ++s) {
            bf16x8 bfr = *(const bf16x8*)((const char*)Bs + (((s * 16 + c) * 64 + l) << 4));
#pragma unroll
            for (int rb = 0; rb < 4; ++rb)
                acc[cl][rb] = __builtin_amdgcn_mfma_f32_16x16x32_bf16(afr[rb][s], bfr, acc[cl][rb], 0, 0, 0);
        }
    }

#pragma unroll
    for (int cl = 0; cl < 4; ++cl)
#pragma unroll
        for (int rb = 0; rb < 4; ++rb)
#pragma unroll
            for (int r = 0; r < 4; ++r) {
                int row = rb * 16 + (l >> 4) * 4 + r;
                if (row < nE)
                    Pb[(size_t)(e0 + row) * 256 + w * 64 + cl * 16 + (l & 15)] = (uint16_t)f2bf(acc[cl][rb][r]);
            }
}

// ---------------------------------------------------------------------------
// counting sort by e_ij: hist -> scan (3 kernels); scatter fused into kSA
// ---------------------------------------------------------------------------
__global__ void khist(const int* __restrict__ tbe, uint32_t* __restrict__ cnt, int T) {
    int t = blockIdx.x * blockDim.x + threadIdx.x;
    int stride = gridDim.x * blockDim.x;
    for (; t < T; t += stride) {
        int2 ee = ((const int2*)tbe)[t];
        atomicAdd(&cnt[ee.x], 1u);
    }
}

__global__ void scanA(const uint32_t* __restrict__ cnt, uint32_t* __restrict__ bsum, int E) {
    __shared__ uint32_t s[256];
    int tid = threadIdx.x;
    int e = blockIdx.x * 256 + tid;
    s[tid] = (e < E) ? cnt[e] : 0u;
    __syncthreads();
    for (int off = 128; off > 0; off >>= 1) {
        if (tid < off) s[tid] += s[tid + off];
        __syncthreads();
    }
    if (tid == 0) bsum[blockIdx.x] = s[0];
}

__global__ void scanB(uint32_t* __restrict__ bsum, int n) {
    __shared__ uint32_t s[512];
    int tid = threadIdx.x;
    s[tid] = (tid < n) ? bsum[tid] : 0u;
    __syncthreads();
    for (int off = 1; off < 512; off <<= 1) {
        uint32_t a = (tid >= off) ? s[tid - off] : 0u;
        __syncthreads();
        s[tid] += a;
        __syncthreads();
    }
    if (tid < n) bsum[tid] = (tid > 0) ? s[tid - 1] : 0u;
}

__global__ void scanC(const uint32_t* __restrict__ cnt, const uint32_t* __restrict__ bsum,
                      uint32_t* __restrict__ offs, int E) {
    __shared__ uint32_t s[256];
    int tid = threadIdx.x;
    int e = blockIdx.x * 256 + tid;
    uint32_t v = (e < E) ? cnt[e] : 0u;
    s[tid] = v;
    __syncthreads();
    for (int off = 1; off < 256; off <<= 1) {
        uint32_t a = (tid >= off) ? s[tid - off] : 0u;
        __syncthreads();
        s[tid] += a;
        __syncthreads();
    }
    if (e < E) offs[e] = bsum[blockIdx.x] + s[tid] - v;   // exclusive start
}

// ---------------------------------------------------------------------------
// kSA: angle MLP over the UNSORTED list; af written COALESCED at t; only the
// 4B permutation sortedT[pos]=t is scattered. Afterwards offs[e] = seg END.
// ---------------------------------------------------------------------------
__global__ void __launch_bounds__(256) kSA(const int* __restrict__ tbe,
                                           const float* __restrict__ evec,
                                           const float* __restrict__ Wa1,
                                           const float* __restrict__ ba1,
                                           const float* __restrict__ Wa2,
                                           const float* __restrict__ ba2,
                                           uint32_t* __restrict__ offs,
                                           uint32_t* __restrict__ afpk,
                                           uint32_t* __restrict__ sortedT, int T) {
    __shared__ float wa1_s[60], ba1_s[NB], wa2_s[400], ba2_s[NB];
    const int tid = threadIdx.x;
    for (int i = tid; i < 400; i += 256) wa2_s[i] = Wa2[i];
    if (tid < 60) wa1_s[tid] = Wa1[tid];
    if (tid < NB) { ba1_s[tid] = ba1[tid]; ba2_s[tid] = ba2[tid]; }
    __syncthreads();

    const int t = blockIdx.x * 256 + tid;
    if (t >= T) return;

    int2 ee = ((const int2*)tbe)[t];
    const float ax = evec[ee.x * 3], ay = evec[ee.x * 3 + 1], az = evec[ee.x * 3 + 2];
    const float bx = evec[ee.y * 3], by = evec[ee.y * 3 + 1], bz = evec[ee.y * 3 + 2];
    const float li = fmaxf(__builtin_amdgcn_sqrtf(ax * ax + ay * ay + az * az), 1e-6f);
    const float lk = fmaxf(__builtin_amdgcn_sqrtf(bx * bx + by * by + bz * bz), 1e-6f);
    float ct = (ax * bx + ay * by + az * bz) * __builtin_amdgcn_rcpf(li * lk);
    ct = fminf(fmaxf(ct, -1.f), 1.f);

    float h[NB];
#pragma unroll
    for (int o = 0; o < NB; ++o) {
        float z = fmaf(li, wa1_s[o], fmaf(lk, wa1_s[20 + o], fmaf(ct, wa1_s[40 + o], ba1_s[o])));
        h[o] = silu_f(z);
    }
    float af[NB];
#pragma unroll
    for (int o2 = 0; o2 < NB; ++o2) af[o2] = ba2_s[o2];
#pragma unroll
    for (int o = 0; o < NB; ++o) {
#pragma unroll
        for (int o2 = 0; o2 < NB; ++o2) af[o2] = fmaf(h[o], wa2_s[o * 20 + o2], af[o2]);
    }

    const uint32_t pos = atomicAdd(&offs[ee.x], 1u);
    sortedT[pos] = (uint32_t)t;
    uint32_t* dst = afpk + (size_t)t * 10;   // coalesced
#pragma unroll
    for (int j = 0; j < 5; ++j) {
        uint2 pk;
        pk.x = pack_bf2(af[4 * j], af[4 * j + 1]);
        pk.y = pack_bf2(af[4 * j + 2], af[4 * j + 3]);
        *(uint2*)(dst + 2 * j) = pk;
    }
}

// ---------------------------------------------------------------------------
// kB6: one wave per EG consecutive edges = one CONTIGUOUS sorted-triplet
// range. Flat 64-triplet windows amortize staging latency over ~6 edges;
// wave-uniform edge-boundary bookkeeping; wreg loaded once per wave.
// ---------------------------------------------------------------------------
__global__ void __launch_bounds__(256) kB6(const uint32_t* __restrict__ sortedT,
                                           const uint32_t* __restrict__ offs,
                                           const int* __restrict__ tbe,
                                           const float* __restrict__ W1,
                                           const float* __restrict__ b1,
                                           const uint32_t* __restrict__ Ppk,
                                           const uint32_t* __restrict__ afpk,
                                           float* __restrict__ S, int E) {
    __shared__ __align__(16) float af_s[4][64 * 20];   // 20KB
    __shared__ uint32_t e2_s[4][64];

    const int tid = threadIdx.x;
    const int wave = tid >> 6, lane = tid & 63;
    const int gw = blockIdx.x * 4 + wave;
    const int eb = gw * EG;
    if (eb >= E) return;   // no block barriers — safe divergence
    const int ee = min(eb + EG, E);

    // lane l (0..EG) holds offs[eb-1+l]; lane 0 of eb==0 holds 0
    uint32_t offv = 0u;
    {
        int oi = eb - 1 + lane;
        if (lane <= EG && oi >= 0) offv = offs[min(oi, E - 1)];
    }
    const uint32_t tstart = __shfl(offv, 0);
    const uint32_t tend = __shfl(offv, ee - eb);

    // W1c fragment (rows 256..275, cols 2*lane, 2*lane+1) — once per wave
    float2 wreg[NB];
#pragma unroll
    for (int k = 0; k < NB; ++k)
        wreg[k] = *(const float2*)(W1 + (size_t)(256 + k) * 128 + 2 * lane);
    const float2 b1v = ((const float2*)b1)[lane];

    int ecur = eb;
    uint32_t eend = __shfl(offv, 1);
    uint32_t p1A = Ppk[(size_t)ecur * 128 + lane];
    uint32_t p1B = Ppk[(size_t)min(ecur + 1, E - 1) * 128 + lane];
    float p1lo = bf_lo(p1A) + b1v.x;
    float p1hi = bf_hi(p1A) + b1v.y;
    float acc0 = 0.f, acc1 = 0.f;

    float* afw = af_s[wave];

    for (uint32_t base = tstart; base < tend; base += 64u) {
        const int m = min(64, (int)(tend - base));
        // ---- stage window: sortedT (coalesced), e2 gather, af gather ----
        const uint32_t idx = min(base + (uint32_t)lane, tend - 1u);
        const uint32_t st = sortedT[idx];
        e2_s[wave][lane] = (uint32_t)(((const int2*)tbe)[st].y);
#pragma unroll
        for (int k = 0; k < 10; ++k) {
            int i = lane + 64 * k;
            int r = i / 10;
            int c = i - r * 10;
            uint32_t str = __shfl(st, r);
            uint32_t u = afpk[(size_t)str * 10 + c];
            afw[2 * i] = bf_lo(u);
            afw[2 * i + 1] = bf_hi(u);
        }
        asm volatile("s_waitcnt lgkmcnt(0)" ::: "memory");
        __builtin_amdgcn_sched_barrier(0);

        // ---- compute with wave-uniform edge boundaries ----
        uint32_t p2a = Ppk[(size_t)e2_s[wave][0] * 128 + 64 + lane];
        uint32_t p2b = (m > 1) ? Ppk[(size_t)e2_s[wave][1] * 128 + 64 + lane] : p2a;
        int i2 = 0;
        while (i2 < m) {
            const uint32_t rem = eend - base;   // eend > base while edges remain
            const int lim = (rem < (uint32_t)m) ? (int)rem : m;
            for (; i2 < lim; ++i2) {
                const uint32_t p2 = p2a;
                p2a = p2b;
                if (i2 + 2 < m) p2b = Ppk[(size_t)e2_s[wave][i2 + 2] * 128 + 64 + lane];
                float x0 = p1lo + bf_lo(p2);
                float x1 = p1hi + bf_hi(p2);
                const float4* afp = (const float4*)(afw + i2 * 20);
                const float4 fA = afp[0], fB = afp[1], fC = afp[2], fD = afp[3], fE = afp[4];
                const float a_[20] = {fA.x, fA.y, fA.z, fA.w, fB.x, fB.y, fB.z, fB.w,
                                      fC.x, fC.y, fC.z, fC.w, fD.x, fD.y, fD.z, fD.w,
                                      fE.x, fE.y, fE.z, fE.w};
#pragma unroll
                for (int j = 0; j < NB; ++j) {
                    x0 = fmaf(a_[j], wreg[j].x, x0);
                    x1 = fmaf(a_[j], wreg[j].y, x1);
                }
                acc0 += silu_f(x0);
                acc1 += silu_f(x1);
            }
            if (base + (uint32_t)i2 == eend) {
                // finalize current edge (and any empty-edge chain)
                do {
                    float2 o;
                    o.x = acc0;
                    o.y = acc1;
                    ((float2*)S)[(size_t)ecur * 64 + lane] = o;
                    acc0 = 0.f;
                    acc1 = 0.f;
                    ++ecur;
                    if (ecur >= ee) { eend = 0xffffffffu; break; }
                    p1A = p1B;
                    p1B = Ppk[(size_t)min(ecur + 1, E - 1) * 128 + lane];
                    p1lo = bf_lo(p1A) + b1v.x;
                    p1hi = bf_hi(p1A) + b1v.y;
                    eend = __shfl(offv, ecur - eb + 1);
                } while (base + (uint32_t)i2 == eend);
            }
        }
    }
    // flush (covers all-empty waves; normally a no-op)
    while (ecur < ee) {
        float2 o;
        o.x = acc0;
        o.y = acc1;
        ((float2*)S)[(size_t)ecur * 64 + lane] = o;
        acc0 = 0.f;
        acc1 = 0.f;
        ++ecur;
    }
}

// ---------------------------------------------------------------------------
// kC2: MFMA out = S @ M + cnt*cvec + bu, in-place. Block: 64 rows x 128 cols.
// ---------------------------------------------------------------------------
__global__ void __launch_bounds__(256) kC2(const float* __restrict__ S,
                                           const uint32_t* __restrict__ Mfrag,
                                           const float* __restrict__ cvec,
                                           const float* __restrict__ bu,
                                           const uint32_t* __restrict__ cnt,
                                           int E) {
    __shared__ uint32_t As[4096];    // 64 x 64 dwords swizzled (16KB)
    __shared__ uint32_t Bs[8192];    // 32KB fragment-ordered M
    __shared__ float cnt_s[64];
    const int tid = threadIdx.x;
    const int e0 = blockIdx.x * 64;
    const int nE = min(64, E - e0);

    for (int d = tid; d < 4096; d += 256) {
        int row = d >> 6, p = d & 63;
        int g = p >> 2;
        float2 v;
        if (row < nE) v = *(const float2*)(S + (size_t)(e0 + row) * 128 + 2 * p);
        else { v.x = 0.f; v.y = 0.f; }
        As[row * 64 + ((g ^ (row & 7)) << 2) + (p & 3)] = pack_bf2(v.x, v.y);
    }
    for (int d = tid; d < 2048; d += 256)
        ((uint4*)Bs)[d] = ((const uint4*)Mfrag)[d];
    if (tid < 64) cnt_s[tid] = (tid < nE) ? (float)cnt[e0 + tid] : 0.f;
    __syncthreads();

    const int w = tid >> 6, l = tid & 63;

    bf16x8 afr[4][4];
#pragma unroll
    for (int rb = 0; rb < 4; ++rb)
#pragma unroll
        for (int s = 0; s < 4; ++s) {
            int row = rb * 16 + (l & 15);
            int g = s * 4 + (l >> 4);
            afr[rb][s] = *(const bf16x8*)((const char*)As + row * 256 + ((g ^ (row & 7)) << 4));
        }

    f32x4 acc[2][4];
#pragma unroll
    for (int cl = 0; cl < 2; ++cl)
#pragma unroll
        for (int rb = 0; rb < 4; ++rb) acc[cl][rb] = (f32x4)(0.f);

#pragma unroll
    for (int cl = 0; cl < 2; ++cl) {
        const int c = w * 2 + cl;
#pragma unroll
        for (int s = 0; s < 4; ++s) {
            bf16x8 bfr = *(const bf16x8*)((const char*)Bs + (((s * 8 + c) * 64 + l) << 4));
#pragma unroll
            for (int rb = 0; rb < 4; ++rb)
                acc[cl][rb] = __builtin_amdgcn_mfma_f32_16x16x32_bf16(afr[rb][s], bfr, acc[cl][rb], 0, 0, 0);
        }
    }

    // epilogue: + cnt*cvec + bu, write fp32 in place
#pragma unroll
    for (int cl = 0; cl < 2; ++cl) {
        const int col = w * 32 + cl * 16 + (l & 15);
        const float cv = cvec[col];
        const float bv = bu[col];
#pragma unroll
        for (int rb = 0; rb < 4; ++rb)
#pragma unroll
            for (int r = 0; r < 4; ++r) {
                int row = rb * 16 + (l >> 4) * 4 + r;
                if (row < nE) {
                    float* dst = (float*)S + (size_t)(e0 + row) * 128 + col;
                    *dst = acc[cl][rb][r] + fmaf(cnt_s[row], cv, bv);
                }
            }
    }
}

// ---------------------------------------------------------------------------
extern "C" void kernel_launch(void* const* d_in, const int* in_sizes, int n_in,
                              void* d_out, int out_size, void* d_ws, size_t ws_size,
                              hipStream_t stream) {
    const float* edge_attr = (const float*)d_in[0];
    // d_in[1]: three_body_indices — unused by the reference computation
    const int* tbe = (const int*)d_in[2];
    const float* evec = (const float*)d_in[3];
    const float* Wa1 = (const float*)d_in[4];
    const float* ba1 = (const float*)d_in[5];
    const float* Wa2 = (const float*)d_in[6];
    const float* ba2 = (const float*)d_in[7];
    const float* W1 = (const float*)d_in[8];
    const float* b1 = (const float*)d_in[9];
    const float* W2 = (const float*)d_in[10];
    const float* b2 = (const float*)d_in[11];
    const float* Wu = (const float*)d_in[12];
    const float* bu = (const float*)d_in[13];

    const int E = in_sizes[0] / 128;
    const int T = in_sizes[2] / 2;
    float* S = (float*)d_out;

    const int nScanBlk = (E + 255) / 256;

    char* ws = (char*)d_ws;
    size_t off = 0;
    uint32_t* Ppk = (uint32_t*)(ws + off); off += (size_t)E * 512;    // bf16 E x 256
    uint32_t* cnt = (uint32_t*)(ws + off); off += (size_t)E * 4;
    uint32_t* offs = (uint32_t*)(ws + off); off += (size_t)E * 4;
    uint32_t* sortedT = (uint32_t*)(ws + off); off += (size_t)T * 4;
    uint32_t* afpk = (uint32_t*)(ws + off); off += (size_t)T * 40;
    uint32_t* bsum = (uint32_t*)(ws + off); off += (size_t)((nScanBlk + 3) & ~3) * 4;
    uint32_t* Bpk = (uint32_t*)(ws + off); off += 65536;
    float* Mf32 = (float*)(ws + off); off += 65536;
    uint32_t* Mfrag = (uint32_t*)(ws + off); off += 32768;
    float* cvec = (float*)(ws + off); off += 512;

    hipMemsetAsync(cnt, 0, (size_t)E * 4, stream);

    prep_kernel<<<129, 64, 0, stream>>>(W2, b2, Wu, Mf32, cvec);
    prep2<<<64, 256, 0, stream>>>(W1, Bpk);
    prepM<<<32, 256, 0, stream>>>(Mf32, Mfrag);
    kA3<<<(E + 63) / 64, 256, 0, stream>>>(edge_attr, Bpk, (uint16_t*)Ppk, E);
    khist<<<2048, 256, 0, stream>>>(tbe, cnt, T);
    scanA<<<nScanBlk, 256, 0, stream>>>(cnt, bsum, E);
    scanB<<<1, 512, 0, stream>>>(bsum, nScanBlk);
    scanC<<<nScanBlk, 256, 0, stream>>>(cnt, bsum, offs, E);
    kSA<<<(T + 255) / 256, 256, 0, stream>>>(tbe, evec, Wa1, ba1, Wa2, ba2,
                                             offs, afpk, sortedT, T);
    const int nWaves = (E + EG - 1) / EG;
    kB6<<<(nWaves + 3) / 4, 256, 0, stream>>>(sortedT, offs, tbe, W1, b1, Ppk, afpk, S, E);
    kC2<<<(E + 63) / 64, 256, 0, stream>>>(S, Mfrag, cvec, bu, cnt, E);
}

// Round 8
// 497.942 us; speedup vs baseline: 1.1305x; 1.1305x over previous
//
#include <hip/hip_runtime.h>
#include <stdint.h>

#define NB 20
#define EG 8    // edges per wave in kB7

typedef __attribute__((ext_vector_type(8))) short bf16x8;
typedef __attribute__((ext_vector_type(4))) float f32x4;

__device__ __forceinline__ float bf_lo(uint32_t u) { return __uint_as_float(u << 16); }
__device__ __forceinline__ float bf_hi(uint32_t u) { return __uint_as_float(u & 0xffff0000u); }
__device__ __forceinline__ uint32_t f2bf(float f) {
    uint32_t u = __float_as_uint(f);
    return (u + 0x7fffu + ((u >> 16) & 1u)) >> 16;  // RNE
}
__device__ __forceinline__ uint32_t pack_bf2(float a, float b) {
    return f2bf(a) | (f2bf(b) << 16);
}
// fast silu: x * rcp(1 + 2^(-x*log2e))
__device__ __forceinline__ float silu_f(float x) {
    float e = __builtin_amdgcn_exp2f(-1.4426950408889634f * x);
    return x * __builtin_amdgcn_rcpf(1.f + e);
}

// ---------------------------------------------------------------------------
// prepA: blocks 0..64  -> Mf32 = W2@Wu, cvec = b2@Wu   (2 rows per block)
//        blocks 65..128 -> W1[0:256] -> bf16 B-fragments (prep2), 16384 dwords
// ---------------------------------------------------------------------------
__global__ void __launch_bounds__(256) prepA(const float* __restrict__ W2,
                                             const float* __restrict__ b2,
                                             const float* __restrict__ Wu,
                                             const float* __restrict__ W1,
                                             float* __restrict__ Mf32,
                                             float* __restrict__ cvec,
                                             uint32_t* __restrict__ Bpk) {
    const int bid = blockIdx.x, tid = threadIdx.x;
    if (bid < 65) {
        int k = bid * 2 + (tid >> 7);
        int col = tid & 127;
        if (k <= 128) {
            const float* row = (k < 128) ? (W2 + k * 128) : b2;
            float acc = 0.f;
            for (int j = 0; j < 128; ++j) acc = fmaf(row[j], Wu[j * 128 + col], acc);
            if (k < 128) Mf32[k * 128 + col] = acc;
            else cvec[col] = acc;
        }
    } else {
        int d = (bid - 65) * 256 + tid;   // 0..16383
        int q = d & 3, l = (d >> 2) & 63, c = (d >> 8) & 15, s = d >> 12;
        int k = 32 * s + ((l >> 4) << 3) + (q << 1);
        int col = (c << 4) + (l & 15);
        int r0 = (col < 128) ? k : (k + 128);
        int cc = col & 127;
        float v0 = W1[(size_t)r0 * 128 + cc];
        float v1 = W1[(size_t)(r0 + 1) * 128 + cc];
        Bpk[d] = pack_bf2(v0, v1);
    }
}

// prepM: Mf32 -> bf16 B-fragments for kC2 (N=128: c 0..7). 8192 dwords.
__global__ void prepM(const float* __restrict__ Mf32, uint32_t* __restrict__ Mfrag) {
    int d = blockIdx.x * 256 + threadIdx.x;   // 0..8191
    int q = d & 3, l = (d >> 2) & 63, c = (d >> 8) & 7, s = d >> 11;
    int k = 32 * s + ((l >> 4) << 3) + (q << 1);
    int col = (c << 4) + (l & 15);
    Mfrag[d] = pack_bf2(Mf32[k * 128 + col], Mf32[(k + 1) * 128 + col]);
}

// ---------------------------------------------------------------------------
// kA3: MFMA GEMM P = edge_attr (E x 128) @ Bcat (128 x 256), bf16 out.
// ---------------------------------------------------------------------------
__global__ void __launch_bounds__(256) kA3(const float* __restrict__ edge_attr,
                                           const uint32_t* __restrict__ Bpk,
                                           uint16_t* __restrict__ Pb, int E) {
    __shared__ uint32_t As[4096];    // 64 rows x 64 dwords (16KB)
    __shared__ uint32_t Bs[16384];   // 64KB fragment-ordered B
    const int tid = threadIdx.x;
    const int e0 = blockIdx.x * 64;
    const int nE = min(64, E - e0);

    for (int d = tid; d < 4096; d += 256) {
        int row = d >> 6, p = d & 63;
        int g = p >> 2;
        float2 v;
        if (row < nE) v = *(const float2*)(edge_attr + (size_t)(e0 + row) * 128 + 2 * p);
        else { v.x = 0.f; v.y = 0.f; }
        As[row * 64 + ((g ^ (row & 7)) << 2) + (p & 3)] = pack_bf2(v.x, v.y);
    }
    for (int d = tid; d < 4096; d += 256)
        ((uint4*)Bs)[d] = ((const uint4*)Bpk)[d];
    __syncthreads();

    const int w = tid >> 6, l = tid & 63;

    bf16x8 afr[4][4];   // [rb][s]
#pragma unroll
    for (int rb = 0; rb < 4; ++rb)
#pragma unroll
        for (int s = 0; s < 4; ++s) {
            int row = rb * 16 + (l & 15);
            int g = s * 4 + (l >> 4);
            afr[rb][s] = *(const bf16x8*)((const char*)As + row * 256 + ((g ^ (row & 7)) << 4));
        }

    f32x4 acc[4][4];    // [cl][rb]
#pragma unroll
    for (int cl = 0; cl < 4; ++cl)
#pragma unroll
        for (int rb = 0; rb < 4; ++rb) acc[cl][rb] = (f32x4)(0.f);

#pragma unroll
    for (int cl = 0; cl < 4; ++cl) {
        const int c = w * 4 + cl;
#pragma unroll
        for (int s = 0; s < 4; ++s) {
            bf16x8 bfr = *(const bf16x8*)((const char*)Bs + (((s * 16 + c) * 64 + l) << 4));
#pragma unroll
            for (int rb = 0; rb < 4; ++rb)
                acc[cl][rb] = __builtin_amdgcn_mfma_f32_16x16x32_bf16(afr[rb][s], bfr, acc[cl][rb], 0, 0, 0);
        }
    }

#pragma unroll
    for (int cl = 0; cl < 4; ++cl)
#pragma unroll
        for (int rb = 0; rb < 4; ++rb)
#pragma unroll
            for (int r = 0; r < 4; ++r) {
                int row = rb * 16 + (l >> 4) * 4 + r;
                if (row < nE)
                    Pb[(size_t)(e0 + row) * 256 + w * 64 + cl * 16 + (l & 15)] = (uint16_t)f2bf(acc[cl][rb][r]);
            }
}

// ---------------------------------------------------------------------------
// counting sort by e_ij: hist -> scan (3 kernels); scatter fused into kSA
// ---------------------------------------------------------------------------
__global__ void khist(const int* __restrict__ tbe, uint32_t* __restrict__ cnt, int T) {
    int t = blockIdx.x * blockDim.x + threadIdx.x;
    int stride = gridDim.x * blockDim.x;
    int half = T >> 1;   // T even (1e6)
    for (; t < half; t += stride) {
        int4 ee = ((const int4*)tbe)[t];
        atomicAdd(&cnt[ee.x], 1u);
        atomicAdd(&cnt[ee.z], 1u);
    }
}

__global__ void scanA(const uint32_t* __restrict__ cnt, uint32_t* __restrict__ bsum, int E) {
    __shared__ uint32_t s[256];
    int tid = threadIdx.x;
    int e = blockIdx.x * 256 + tid;
    s[tid] = (e < E) ? cnt[e] : 0u;
    __syncthreads();
    for (int off = 128; off > 0; off >>= 1) {
        if (tid < off) s[tid] += s[tid + off];
        __syncthreads();
    }
    if (tid == 0) bsum[blockIdx.x] = s[0];
}

__global__ void scanB(uint32_t* __restrict__ bsum, int n) {
    __shared__ uint32_t s[512];
    int tid = threadIdx.x;
    s[tid] = (tid < n) ? bsum[tid] : 0u;
    __syncthreads();
    for (int off = 1; off < 512; off <<= 1) {
        uint32_t a = (tid >= off) ? s[tid - off] : 0u;
        __syncthreads();
        s[tid] += a;
        __syncthreads();
    }
    if (tid < n) bsum[tid] = (tid > 0) ? s[tid - 1] : 0u;
}

__global__ void scanC(const uint32_t* __restrict__ cnt, const uint32_t* __restrict__ bsum,
                      uint32_t* __restrict__ offs, int E) {
    __shared__ uint32_t s[256];
    int tid = threadIdx.x;
    int e = blockIdx.x * 256 + tid;
    uint32_t v = (e < E) ? cnt[e] : 0u;
    s[tid] = v;
    __syncthreads();
    for (int off = 1; off < 256; off <<= 1) {
        uint32_t a = (tid >= off) ? s[tid - off] : 0u;
        __syncthreads();
        s[tid] += a;
        __syncthreads();
    }
    if (e < E) offs[e] = bsum[blockIdx.x] + s[tid] - v;   // exclusive start
}

// ---------------------------------------------------------------------------
// kSA: fused scatter + angle MLP over the UNSORTED list; writes af (bf16
// pairs) and e2 at sorted pos. Afterwards offs[e] = segment END.
// ---------------------------------------------------------------------------
__global__ void __launch_bounds__(256) kSA(const int* __restrict__ tbe,
                                           const float* __restrict__ evec,
                                           const float* __restrict__ Wa1,
                                           const float* __restrict__ ba1,
                                           const float* __restrict__ Wa2,
                                           const float* __restrict__ ba2,
                                           uint32_t* __restrict__ offs,
                                           uint32_t* __restrict__ afpk,
                                           uint32_t* __restrict__ sortedE2, int T) {
    __shared__ float wa1_s[60], ba1_s[NB], wa2_s[400], ba2_s[NB];
    const int tid = threadIdx.x;
    for (int i = tid; i < 400; i += 256) wa2_s[i] = Wa2[i];
    if (tid < 60) wa1_s[tid] = Wa1[tid];
    if (tid < NB) { ba1_s[tid] = ba1[tid]; ba2_s[tid] = ba2[tid]; }
    __syncthreads();

    const int t = blockIdx.x * 256 + tid;
    if (t >= T) return;

    int2 ee = ((const int2*)tbe)[t];
    const float ax = evec[ee.x * 3], ay = evec[ee.x * 3 + 1], az = evec[ee.x * 3 + 2];
    const float bx = evec[ee.y * 3], by = evec[ee.y * 3 + 1], bz = evec[ee.y * 3 + 2];
    const float li = fmaxf(__builtin_amdgcn_sqrtf(ax * ax + ay * ay + az * az), 1e-6f);
    const float lk = fmaxf(__builtin_amdgcn_sqrtf(bx * bx + by * by + bz * bz), 1e-6f);
    float ct = (ax * bx + ay * by + az * bz) * __builtin_amdgcn_rcpf(li * lk);
    ct = fminf(fmaxf(ct, -1.f), 1.f);

    float h[NB];
#pragma unroll
    for (int o = 0; o < NB; ++o) {
        float z = fmaf(li, wa1_s[o], fmaf(lk, wa1_s[20 + o], fmaf(ct, wa1_s[40 + o], ba1_s[o])));
        h[o] = silu_f(z);
    }
    float af[NB];
#pragma unroll
    for (int o2 = 0; o2 < NB; ++o2) af[o2] = ba2_s[o2];
#pragma unroll
    for (int o = 0; o < NB; ++o) {
#pragma unroll
        for (int o2 = 0; o2 < NB; ++o2) af[o2] = fmaf(h[o], wa2_s[o * 20 + o2], af[o2]);
    }

    const uint32_t pos = atomicAdd(&offs[ee.x], 1u);
    sortedE2[pos] = (uint32_t)ee.y;
    uint32_t* dst = afpk + (size_t)pos * 10;
#pragma unroll
    for (int j = 0; j < 5; ++j) {
        uint2 pk;
        pk.x = pack_bf2(af[4 * j], af[4 * j + 1]);
        pk.y = pack_bf2(af[4 * j + 2], af[4 * j + 3]);
        *(uint2*)(dst + 2 * j) = pk;
    }
}

// ---------------------------------------------------------------------------
// kB7: one wave per EG consecutive edges = one CONTIGUOUS sorted-triplet
// range. Flat 64-triplet windows staged from CONTIGUOUS afpk/sortedE2
// (sorted layout, r6 style); wave-uniform edge-boundary bookkeeping
// (verified in r7); wreg loaded once per wave.
// ---------------------------------------------------------------------------
__global__ void __launch_bounds__(256) kB7(const uint32_t* __restrict__ sortedE2,
                                           const uint32_t* __restrict__ offs,
                                           const float* __restrict__ W1,
                                           const float* __restrict__ b1,
                                           const uint32_t* __restrict__ Ppk,
                                           const uint32_t* __restrict__ afpk,
                                           float* __restrict__ S, int E) {
    __shared__ __align__(16) float af_s[4][64 * 20];   // 20KB
    __shared__ uint32_t e2_s[4][64];

    const int tid = threadIdx.x;
    const int wave = tid >> 6, lane = tid & 63;
    const int gw = blockIdx.x * 4 + wave;
    const int eb = gw * EG;
    if (eb >= E) return;   // no block barriers — safe divergence
    const int ee = min(eb + EG, E);

    // lane l (0..EG) holds offs[eb-1+l]; lane 0 of eb==0 holds 0
    uint32_t offv = 0u;
    {
        int oi = eb - 1 + lane;
        if (lane <= EG && oi >= 0) offv = offs[min(oi, E - 1)];
    }
    const uint32_t tstart = __shfl(offv, 0);
    const uint32_t tend = __shfl(offv, ee - eb);

    // W1c fragment (rows 256..275, cols 2*lane, 2*lane+1) — once per wave
    float2 wreg[NB];
#pragma unroll
    for (int k = 0; k < NB; ++k)
        wreg[k] = *(const float2*)(W1 + (size_t)(256 + k) * 128 + 2 * lane);
    const float2 b1v = ((const float2*)b1)[lane];

    int ecur = eb;
    uint32_t eend = __shfl(offv, 1);
    uint32_t p1A = Ppk[(size_t)ecur * 128 + lane];
    uint32_t p1B = Ppk[(size_t)min(ecur + 1, E - 1) * 128 + lane];
    float p1lo = bf_lo(p1A) + b1v.x;
    float p1hi = bf_hi(p1A) + b1v.y;
    float acc0 = 0.f, acc1 = 0.f;

    float* afw = af_s[wave];

    for (uint32_t base = tstart; base < tend; base += 64u) {
        const int m = min(64, (int)(tend - base));
        // ---- stage window: sortedE2 + afpk, both CONTIGUOUS ----
        const uint32_t idx = min(base + (uint32_t)lane, tend - 1u);
        e2_s[wave][lane] = sortedE2[idx];
        const uint32_t base10 = base * 10u;
        for (int i = lane; i < m * 10; i += 64) {
            const uint32_t u = afpk[base10 + i];
            afw[2 * i] = bf_lo(u);
            afw[2 * i + 1] = bf_hi(u);
        }
        asm volatile("s_waitcnt lgkmcnt(0)" ::: "memory");
        __builtin_amdgcn_sched_barrier(0);

        // ---- compute with wave-uniform edge boundaries ----
        uint32_t p2a = Ppk[(size_t)e2_s[wave][0] * 128 + 64 + lane];
        uint32_t p2b = (m > 1) ? Ppk[(size_t)e2_s[wave][1] * 128 + 64 + lane] : p2a;
        int i2 = 0;
        while (i2 < m) {
            const uint32_t rem = eend - base;   // eend > base while edges remain
            const int lim = (rem < (uint32_t)m) ? (int)rem : m;
            for (; i2 < lim; ++i2) {
                const uint32_t p2 = p2a;
                p2a = p2b;
                if (i2 + 2 < m) p2b = Ppk[(size_t)e2_s[wave][i2 + 2] * 128 + 64 + lane];
                float x0 = p1lo + bf_lo(p2);
                float x1 = p1hi + bf_hi(p2);
                const float4* afp = (const float4*)(afw + i2 * 20);
                const float4 fA = afp[0], fB = afp[1], fC = afp[2], fD = afp[3], fE = afp[4];
                const float a_[20] = {fA.x, fA.y, fA.z, fA.w, fB.x, fB.y, fB.z, fB.w,
                                      fC.x, fC.y, fC.z, fC.w, fD.x, fD.y, fD.z, fD.w,
                                      fE.x, fE.y, fE.z, fE.w};
#pragma unroll
                for (int j = 0; j < NB; ++j) {
                    x0 = fmaf(a_[j], wreg[j].x, x0);
                    x1 = fmaf(a_[j], wreg[j].y, x1);
                }
                acc0 += silu_f(x0);
                acc1 += silu_f(x1);
            }
            if (base + (uint32_t)i2 == eend) {
                // finalize current edge (and any empty-edge chain)
                do {
                    float2 o;
                    o.x = acc0;
                    o.y = acc1;
                    ((float2*)S)[(size_t)ecur * 64 + lane] = o;
                    acc0 = 0.f;
                    acc1 = 0.f;
                    ++ecur;
                    if (ecur >= ee) { eend = 0xffffffffu; break; }
                    p1A = p1B;
                    p1B = Ppk[(size_t)min(ecur + 1, E - 1) * 128 + lane];
                    p1lo = bf_lo(p1A) + b1v.x;
                    p1hi = bf_hi(p1A) + b1v.y;
                    eend = __shfl(offv, ecur - eb + 1);
                } while (base + (uint32_t)i2 == eend);
            }
        }
    }
    // flush (covers all-empty waves; normally a no-op)
    while (ecur < ee) {
        float2 o;
        o.x = acc0;
        o.y = acc1;
        ((float2*)S)[(size_t)ecur * 64 + lane] = o;
        acc0 = 0.f;
        acc1 = 0.f;
        ++ecur;
    }
}

// ---------------------------------------------------------------------------
// kC2: MFMA out = S @ M + cnt*cvec + bu, in-place. Block: 64 rows x 128 cols.
// ---------------------------------------------------------------------------
__global__ void __launch_bounds__(256) kC2(const float* __restrict__ S,
                                           const uint32_t* __restrict__ Mfrag,
                                           const float* __restrict__ cvec,
                                           const float* __restrict__ bu,
                                           const uint32_t* __restrict__ cnt,
                                           int E) {
    __shared__ uint32_t As[4096];    // 64 x 64 dwords swizzled (16KB)
    __shared__ uint32_t Bs[8192];    // 32KB fragment-ordered M
    __shared__ float cnt_s[64];
    const int tid = threadIdx.x;
    const int e0 = blockIdx.x * 64;
    const int nE = min(64, E - e0);

    for (int d = tid; d < 4096; d += 256) {
        int row = d >> 6, p = d & 63;
        int g = p >> 2;
        float2 v;
        if (row < nE) v = *(const float2*)(S + (size_t)(e0 + row) * 128 + 2 * p);
        else { v.x = 0.f; v.y = 0.f; }
        As[row * 64 + ((g ^ (row & 7)) << 2) + (p & 3)] = pack_bf2(v.x, v.y);
    }
    for (int d = tid; d < 2048; d += 256)
        ((uint4*)Bs)[d] = ((const uint4*)Mfrag)[d];
    if (tid < 64) cnt_s[tid] = (tid < nE) ? (float)cnt[e0 + tid] : 0.f;
    __syncthreads();

    const int w = tid >> 6, l = tid & 63;

    bf16x8 afr[4][4];
#pragma unroll
    for (int rb = 0; rb < 4; ++rb)
#pragma unroll
        for (int s = 0; s < 4; ++s) {
            int row = rb * 16 + (l & 15);
            int g = s * 4 + (l >> 4);
            afr[rb][s] = *(const bf16x8*)((const char*)As + row * 256 + ((g ^ (row & 7)) << 4));
        }

    f32x4 acc[2][4];
#pragma unroll
    for (int cl = 0; cl < 2; ++cl)
#pragma unroll
        for (int rb = 0; rb < 4; ++rb) acc[cl][rb] = (f32x4)(0.f);

#pragma unroll
    for (int cl = 0; cl < 2; ++cl) {
        const int c = w * 2 + cl;
#pragma unroll
        for (int s = 0; s < 4; ++s) {
            bf16x8 bfr = *(const bf16x8*)((const char*)Bs + (((s * 8 + c) * 64 + l) << 4));
#pragma unroll
            for (int rb = 0; rb < 4; ++rb)
                acc[cl][rb] = __builtin_amdgcn_mfma_f32_16x16x32_bf16(afr[rb][s], bfr, acc[cl][rb], 0, 0, 0);
        }
    }

    // epilogue: + cnt*cvec + bu, write fp32 in place
#pragma unroll
    for (int cl = 0; cl < 2; ++cl) {
        const int col = w * 32 + cl * 16 + (l & 15);
        const float cv = cvec[col];
        const float bv = bu[col];
#pragma unroll
        for (int rb = 0; rb < 4; ++rb)
#pragma unroll
            for (int r = 0; r < 4; ++r) {
                int row = rb * 16 + (l >> 4) * 4 + r;
                if (row < nE) {
                    float* dst = (float*)S + (size_t)(e0 + row) * 128 + col;
                    *dst = acc[cl][rb][r] + fmaf(cnt_s[row], cv, bv);
                }
            }
    }
}

// ---------------------------------------------------------------------------
extern "C" void kernel_launch(void* const* d_in, const int* in_sizes, int n_in,
                              void* d_out, int out_size, void* d_ws, size_t ws_size,
                              hipStream_t stream) {
    const float* edge_attr = (const float*)d_in[0];
    // d_in[1]: three_body_indices — unused by the reference computation
    const int* tbe = (const int*)d_in[2];
    const float* evec = (const float*)d_in[3];
    const float* Wa1 = (const float*)d_in[4];
    const float* ba1 = (const float*)d_in[5];
    const float* Wa2 = (const float*)d_in[6];
    const float* ba2 = (const float*)d_in[7];
    const float* W1 = (const float*)d_in[8];
    const float* b1 = (const float*)d_in[9];
    const float* W2 = (const float*)d_in[10];
    const float* b2 = (const float*)d_in[11];
    const float* Wu = (const float*)d_in[12];
    const float* bu = (const float*)d_in[13];

    const int E = in_sizes[0] / 128;
    const int T = in_sizes[2] / 2;
    float* S = (float*)d_out;

    const int nScanBlk = (E + 255) / 256;

    char* ws = (char*)d_ws;
    size_t off = 0;
    uint32_t* Ppk = (uint32_t*)(ws + off); off += (size_t)E * 512;    // bf16 E x 256
    uint32_t* cnt = (uint32_t*)(ws + off); off += (size_t)E * 4;
    uint32_t* offs = (uint32_t*)(ws + off); off += (size_t)E * 4;
    uint32_t* sortedE2 = (uint32_t*)(ws + off); off += (size_t)T * 4;
    uint32_t* afpk = (uint32_t*)(ws + off); off += (size_t)T * 40;
    uint32_t* bsum = (uint32_t*)(ws + off); off += (size_t)((nScanBlk + 3) & ~3) * 4;
    uint32_t* Bpk = (uint32_t*)(ws + off); off += 65536;
    float* Mf32 = (float*)(ws + off); off += 65536;
    uint32_t* Mfrag = (uint32_t*)(ws + off); off += 32768;
    float* cvec = (float*)(ws + off); off += 512;

    hipMemsetAsync(cnt, 0, (size_t)E * 4, stream);

    prepA<<<129, 256, 0, stream>>>(W2, b2, Wu, W1, Mf32, cvec, Bpk);
    prepM<<<32, 256, 0, stream>>>(Mf32, Mfrag);
    kA3<<<(E + 63) / 64, 256, 0, stream>>>(edge_attr, Bpk, (uint16_t*)Ppk, E);
    khist<<<1024, 256, 0, stream>>>(tbe, cnt, T);
    scanA<<<nScanBlk, 256, 0, stream>>>(cnt, bsum, E);
    scanB<<<1, 512, 0, stream>>>(bsum, nScanBlk);
    scanC<<<nScanBlk, 256, 0, stream>>>(cnt, bsum, offs, E);
    kSA<<<(T + 255) / 256, 256, 0, stream>>>(tbe, evec, Wa1, ba1, Wa2, ba2,
                                             offs, afpk, sortedE2, T);
    const int nWaves = (E + EG - 1) / EG;
    kB7<<<(nWaves + 3) / 4, 256, 0, stream>>>(sortedE2, offs, W1, b1, Ppk, afpk, S, E);
    kC2<<<(E + 63) / 64, 256, 0, stream>>>(S, Mfrag, cvec, bu, cnt, E);
}

// Round 9
// 463.508 us; speedup vs baseline: 1.2145x; 1.0743x over previous
//
#include <hip/hip_runtime.h>
#include <stdint.h>

#define NB 20
#define EG 8    // edges per wave in kB8

typedef __attribute__((ext_vector_type(8))) short bf16x8;
typedef __attribute__((ext_vector_type(4))) float f32x4;
typedef _Float16 h16x2 __attribute__((ext_vector_type(2)));

__device__ __forceinline__ float bf_lo(uint32_t u) { return __uint_as_float(u << 16); }
__device__ __forceinline__ float bf_hi(uint32_t u) { return __uint_as_float(u & 0xffff0000u); }
__device__ __forceinline__ uint32_t f2bf(float f) {
    uint32_t u = __float_as_uint(f);
    return (u + 0x7fffu + ((u >> 16) & 1u)) >> 16;  // RNE
}
__device__ __forceinline__ uint32_t pack_bf2(float a, float b) {
    return f2bf(a) | (f2bf(b) << 16);
}
__device__ __forceinline__ uint32_t pack_h2(float a, float b) {
    return __builtin_bit_cast(uint32_t, __builtin_amdgcn_cvt_pkrtz(a, b));
}
// fast silu: x * rcp(1 + 2^(-x*log2e))
__device__ __forceinline__ float silu_f(float x) {
    float e = __builtin_amdgcn_exp2f(-1.4426950408889634f * x);
    return x * __builtin_amdgcn_rcpf(1.f + e);
}

// ---------------------------------------------------------------------------
// prepA: bid 0..64   -> M=W2@Wu rows (2bid,2bid+1) -> Mfrag dwords; bid64: cvec
//        bid 65..128 -> W1[0:256] -> bf16 B-fragments for kA3 (16384 dwords)
//        bid 129     -> W1c rows 256..275 -> f16 k-pair pack [10][128] dwords
// ---------------------------------------------------------------------------
__global__ void __launch_bounds__(256) prepA(const float* __restrict__ W2,
                                             const float* __restrict__ b2,
                                             const float* __restrict__ Wu,
                                             const float* __restrict__ W1,
                                             float* __restrict__ cvec,
                                             uint32_t* __restrict__ Bpk,
                                             uint32_t* __restrict__ W1cf16,
                                             uint32_t* __restrict__ Mfrag) {
    const int bid = blockIdx.x, tid = threadIdx.x;
    if (bid < 65) {
        __shared__ float mrow[2][128];
        const int half = tid >> 7;
        const int k = bid * 2 + half;          // 0..129
        const int col = tid & 127;
        float acc = 0.f;
        if (k <= 128) {
            const float* row = (k < 128) ? (W2 + k * 128) : b2;
            for (int j = 0; j < 128; ++j) acc = fmaf(row[j], Wu[j * 128 + col], acc);
        }
        if (k == 128) cvec[col] = acc;
        mrow[half][col] = acc;
        __syncthreads();
        if (bid < 64 && half == 0) {
            // fragment dword for k-pair kk=2*bid (matches prepM algebra)
            const int kk = bid * 2;
            const int s = kk >> 5;
            const int lhi = (kk & 31) >> 3;
            const int q = (kk & 7) >> 1;
            const int c = col >> 4;
            const int l = (lhi << 4) | (col & 15);
            Mfrag[((s * 8 + c) * 64 + l) * 4 + q] = pack_bf2(mrow[0][col], mrow[1][col]);
        }
    } else if (bid < 129) {
        int d = (bid - 65) * 256 + tid;   // 0..16383
        int q = d & 3, l = (d >> 2) & 63, c = (d >> 8) & 15, s = d >> 12;
        int k = 32 * s + ((l >> 4) << 3) + (q << 1);
        int col = (c << 4) + (l & 15);
        int r0 = (col < 128) ? k : (k + 128);
        int cc = col & 127;
        float v0 = W1[(size_t)r0 * 128 + cc];
        float v1 = W1[(size_t)(r0 + 1) * 128 + cc];
        Bpk[d] = pack_bf2(v0, v1);
    } else {
        // W1cf16[j2*128 + c] = pack_h2(W1c[2j2][c], W1c[2j2+1][c]); 1280 dwords
        for (int d = tid; d < 1280; d += 256) {
            int j2 = d >> 7, c = d & 127;
            float v0 = W1[(size_t)(256 + 2 * j2) * 128 + c];
            float v1 = W1[(size_t)(257 + 2 * j2) * 128 + c];
            W1cf16[d] = pack_h2(v0, v1);
        }
    }
}

// ---------------------------------------------------------------------------
// kA3: MFMA GEMM P = edge_attr (E x 128) @ Bcat (128 x 256), bf16 out.
// ---------------------------------------------------------------------------
__global__ void __launch_bounds__(256) kA3(const float* __restrict__ edge_attr,
                                           const uint32_t* __restrict__ Bpk,
                                           uint16_t* __restrict__ Pb, int E) {
    __shared__ uint32_t As[4096];    // 64 rows x 64 dwords (16KB)
    __shared__ uint32_t Bs[16384];   // 64KB fragment-ordered B
    const int tid = threadIdx.x;
    const int e0 = blockIdx.x * 64;
    const int nE = min(64, E - e0);

    for (int d = tid; d < 4096; d += 256) {
        int row = d >> 6, p = d & 63;
        int g = p >> 2;
        float2 v;
        if (row < nE) v = *(const float2*)(edge_attr + (size_t)(e0 + row) * 128 + 2 * p);
        else { v.x = 0.f; v.y = 0.f; }
        As[row * 64 + ((g ^ (row & 7)) << 2) + (p & 3)] = pack_bf2(v.x, v.y);
    }
    for (int d = tid; d < 4096; d += 256)
        ((uint4*)Bs)[d] = ((const uint4*)Bpk)[d];
    __syncthreads();

    const int w = tid >> 6, l = tid & 63;

    bf16x8 afr[4][4];   // [rb][s]
#pragma unroll
    for (int rb = 0; rb < 4; ++rb)
#pragma unroll
        for (int s = 0; s < 4; ++s) {
            int row = rb * 16 + (l & 15);
            int g = s * 4 + (l >> 4);
            afr[rb][s] = *(const bf16x8*)((const char*)As + row * 256 + ((g ^ (row & 7)) << 4));
        }

    f32x4 acc[4][4];    // [cl][rb]
#pragma unroll
    for (int cl = 0; cl < 4; ++cl)
#pragma unroll
        for (int rb = 0; rb < 4; ++rb) acc[cl][rb] = (f32x4)(0.f);

#pragma unroll
    for (int cl = 0; cl < 4; ++cl) {
        const int c = w * 4 + cl;
#pragma unroll
        for (int s = 0; s < 4; ++s) {
            bf16x8 bfr = *(const bf16x8*)((const char*)Bs + (((s * 16 + c) * 64 + l) << 4));
#pragma unroll
            for (int rb = 0; rb < 4; ++rb)
                acc[cl][rb] = __builtin_amdgcn_mfma_f32_16x16x32_bf16(afr[rb][s], bfr, acc[cl][rb], 0, 0, 0);
        }
    }

#pragma unroll
    for (int cl = 0; cl < 4; ++cl)
#pragma unroll
        for (int rb = 0; rb < 4; ++rb)
#pragma unroll
            for (int r = 0; r < 4; ++r) {
                int row = rb * 16 + (l >> 4) * 4 + r;
                if (row < nE)
                    Pb[(size_t)(e0 + row) * 256 + w * 64 + cl * 16 + (l & 15)] = (uint16_t)f2bf(acc[cl][rb][r]);
            }
}

// ---------------------------------------------------------------------------
// counting sort by e_ij: hist -> scan (3 kernels); scatter fused into kSA
// ---------------------------------------------------------------------------
__global__ void khist(const int* __restrict__ tbe, uint32_t* __restrict__ cnt, int T) {
    int t = blockIdx.x * blockDim.x + threadIdx.x;
    int stride = gridDim.x * blockDim.x;
    int half = T >> 1;   // T even (1e6)
    for (; t < half; t += stride) {
        int4 ee = ((const int4*)tbe)[t];
        atomicAdd(&cnt[ee.x], 1u);
        atomicAdd(&cnt[ee.z], 1u);
    }
}

__global__ void scanA(const uint32_t* __restrict__ cnt, uint32_t* __restrict__ bsum, int E) {
    __shared__ uint32_t s[256];
    int tid = threadIdx.x;
    int e = blockIdx.x * 256 + tid;
    s[tid] = (e < E) ? cnt[e] : 0u;
    __syncthreads();
    for (int off = 128; off > 0; off >>= 1) {
        if (tid < off) s[tid] += s[tid + off];
        __syncthreads();
    }
    if (tid == 0) bsum[blockIdx.x] = s[0];
}

__global__ void scanB(uint32_t* __restrict__ bsum, int n) {
    __shared__ uint32_t s[512];
    int tid = threadIdx.x;
    s[tid] = (tid < n) ? bsum[tid] : 0u;
    __syncthreads();
    for (int off = 1; off < 512; off <<= 1) {
        uint32_t a = (tid >= off) ? s[tid - off] : 0u;
        __syncthreads();
        s[tid] += a;
        __syncthreads();
    }
    if (tid < n) bsum[tid] = (tid > 0) ? s[tid - 1] : 0u;
}

__global__ void scanC(const uint32_t* __restrict__ cnt, const uint32_t* __restrict__ bsum,
                      uint32_t* __restrict__ offs, int E) {
    __shared__ uint32_t s[256];
    int tid = threadIdx.x;
    int e = blockIdx.x * 256 + tid;
    uint32_t v = (e < E) ? cnt[e] : 0u;
    s[tid] = v;
    __syncthreads();
    for (int off = 1; off < 256; off <<= 1) {
        uint32_t a = (tid >= off) ? s[tid - off] : 0u;
        __syncthreads();
        s[tid] += a;
        __syncthreads();
    }
    if (e < E) offs[e] = bsum[blockIdx.x] + s[tid] - v;   // exclusive start
}

// ---------------------------------------------------------------------------
// kSA: fused scatter + angle MLP over the UNSORTED list; writes af (f16
// pairs, k-paired) and e2 at sorted pos. Afterwards offs[e] = segment END.
// ---------------------------------------------------------------------------
__global__ void __launch_bounds__(256) kSA(const int* __restrict__ tbe,
                                           const float* __restrict__ evec,
                                           const float* __restrict__ Wa1,
                                           const float* __restrict__ ba1,
                                           const float* __restrict__ Wa2,
                                           const float* __restrict__ ba2,
                                           uint32_t* __restrict__ offs,
                                           uint32_t* __restrict__ afpk,
                                           uint32_t* __restrict__ sortedE2, int T) {
    __shared__ float wa1_s[60], ba1_s[NB], wa2_s[400], ba2_s[NB];
    const int tid = threadIdx.x;
    for (int i = tid; i < 400; i += 256) wa2_s[i] = Wa2[i];
    if (tid < 60) wa1_s[tid] = Wa1[tid];
    if (tid < NB) { ba1_s[tid] = ba1[tid]; ba2_s[tid] = ba2[tid]; }
    __syncthreads();

    const int t = blockIdx.x * 256 + tid;
    if (t >= T) return;

    int2 ee = ((const int2*)tbe)[t];
    const float ax = evec[ee.x * 3], ay = evec[ee.x * 3 + 1], az = evec[ee.x * 3 + 2];
    const float bx = evec[ee.y * 3], by = evec[ee.y * 3 + 1], bz = evec[ee.y * 3 + 2];
    const float li = fmaxf(__builtin_amdgcn_sqrtf(ax * ax + ay * ay + az * az), 1e-6f);
    const float lk = fmaxf(__builtin_amdgcn_sqrtf(bx * bx + by * by + bz * bz), 1e-6f);
    float ct = (ax * bx + ay * by + az * bz) * __builtin_amdgcn_rcpf(li * lk);
    ct = fminf(fmaxf(ct, -1.f), 1.f);

    float h[NB];
#pragma unroll
    for (int o = 0; o < NB; ++o) {
        float z = fmaf(li, wa1_s[o], fmaf(lk, wa1_s[20 + o], fmaf(ct, wa1_s[40 + o], ba1_s[o])));
        h[o] = silu_f(z);
    }
    float af[NB];
#pragma unroll
    for (int o2 = 0; o2 < NB; ++o2) af[o2] = ba2_s[o2];
#pragma unroll
    for (int o = 0; o < NB; ++o) {
#pragma unroll
        for (int o2 = 0; o2 < NB; ++o2) af[o2] = fmaf(h[o], wa2_s[o * 20 + o2], af[o2]);
    }

    const uint32_t pos = atomicAdd(&offs[ee.x], 1u);
    sortedE2[pos] = (uint32_t)ee.y;
    uint32_t* dst = afpk + (size_t)pos * 10;
#pragma unroll
    for (int j = 0; j < 5; ++j) {
        uint2 pk;
        pk.x = pack_h2(af[4 * j], af[4 * j + 1]);
        pk.y = pack_h2(af[4 * j + 2], af[4 * j + 3]);
        *(uint2*)(dst + 2 * j) = pk;
    }
}

// ---------------------------------------------------------------------------
// kB8: one wave per EG consecutive edges (contiguous sorted-triplet range).
// af kept PACKED f16 in LDS (10 dwords/triplet, broadcast reads); af@W1c via
// v_dot2_f32_f16 (20 insts instead of 40 FMA); W1c f16 pairs in 20 VGPRs.
// ---------------------------------------------------------------------------
__global__ void __launch_bounds__(256) kB8(const uint32_t* __restrict__ sortedE2,
                                           const uint32_t* __restrict__ offs,
                                           const uint32_t* __restrict__ W1cf16,
                                           const float* __restrict__ b1,
                                           const uint32_t* __restrict__ Ppk,
                                           const uint32_t* __restrict__ afpk,
                                           float* __restrict__ S, int E) {
    __shared__ __align__(8) uint32_t af_s[4][64 * 10];   // 10KB packed f16
    __shared__ uint32_t e2_s[4][64];

    const int tid = threadIdx.x;
    const int wave = tid >> 6, lane = tid & 63;
    const int gw = blockIdx.x * 4 + wave;
    const int eb = gw * EG;
    if (eb >= E) return;   // no block barriers — safe divergence
    const int ee = min(eb + EG, E);

    // lane l (0..EG) holds offs[eb-1+l]; lane 0 of eb==0 holds 0
    uint32_t offv = 0u;
    {
        int oi = eb - 1 + lane;
        if (lane <= EG && oi >= 0) offv = offs[min(oi, E - 1)];
    }
    const uint32_t tstart = __shfl(offv, 0);
    const uint32_t tend = __shfl(offv, ee - eb);

    // W1c f16 k-pair fragments (cols 2*lane, 2*lane+1) — once per wave
    h16x2 wx[10], wy[10];
#pragma unroll
    for (int j = 0; j < 10; ++j) {
        uint2 w2 = *(const uint2*)(W1cf16 + j * 128 + 2 * lane);
        wx[j] = __builtin_bit_cast(h16x2, w2.x);
        wy[j] = __builtin_bit_cast(h16x2, w2.y);
    }
    const float2 b1v = ((const float2*)b1)[lane];

    int ecur = eb;
    uint32_t eend = __shfl(offv, 1);
    uint32_t p1A = Ppk[(size_t)ecur * 128 + lane];
    uint32_t p1B = Ppk[(size_t)min(ecur + 1, E - 1) * 128 + lane];
    float p1lo = bf_lo(p1A) + b1v.x;
    float p1hi = bf_hi(p1A) + b1v.y;
    float acc0 = 0.f, acc1 = 0.f;

    uint32_t* afw = af_s[wave];

    for (uint32_t base = tstart; base < tend; base += 64u) {
        const int m = min(64, (int)(tend - base));
        // ---- stage window: e2 (clamped) + af row-per-lane, both contiguous ----
        const uint32_t idx = min(base + (uint32_t)lane, tend - 1u);
        e2_s[wave][lane] = sortedE2[idx];
        {
            const uint32_t* src = afpk + ((size_t)base + (uint32_t)lane) * 10u;  // padded past T
            uint32_t* dst = afw + lane * 10;
            uint2 s0 = *(const uint2*)(src);
            uint2 s1 = *(const uint2*)(src + 2);
            uint2 s2 = *(const uint2*)(src + 4);
            uint2 s3 = *(const uint2*)(src + 6);
            uint2 s4 = *(const uint2*)(src + 8);
            *(uint2*)(dst) = s0;
            *(uint2*)(dst + 2) = s1;
            *(uint2*)(dst + 4) = s2;
            *(uint2*)(dst + 6) = s3;
            *(uint2*)(dst + 8) = s4;
        }
        asm volatile("s_waitcnt lgkmcnt(0)" ::: "memory");
        __builtin_amdgcn_sched_barrier(0);

        // ---- compute with wave-uniform edge boundaries ----
        uint32_t p2a = Ppk[(size_t)e2_s[wave][0] * 128 + 64 + lane];
        uint32_t p2b = (m > 1) ? Ppk[(size_t)e2_s[wave][1] * 128 + 64 + lane] : p2a;
        int i2 = 0;
        while (i2 < m) {
            const uint32_t rem = eend - base;   // eend > base while edges remain
            const int lim = (rem < (uint32_t)m) ? (int)rem : m;
            for (; i2 < lim; ++i2) {
                const uint32_t p2 = p2a;
                p2a = p2b;
                if (i2 + 2 < m) p2b = Ppk[(size_t)e2_s[wave][i2 + 2] * 128 + 64 + lane];
                const uint32_t* afp = afw + i2 * 10;    // broadcast reads
                uint2 u0 = *(const uint2*)(afp);
                uint2 u1 = *(const uint2*)(afp + 2);
                uint2 u2 = *(const uint2*)(afp + 4);
                uint2 u3 = *(const uint2*)(afp + 6);
                uint2 u4 = *(const uint2*)(afp + 8);
                const uint32_t aw[10] = {u0.x, u0.y, u1.x, u1.y, u2.x,
                                         u2.y, u3.x, u3.y, u4.x, u4.y};
                float x0 = p1lo + bf_lo(p2);
                float x1 = p1hi + bf_hi(p2);
#pragma unroll
                for (int j = 0; j < 10; ++j) {
                    h16x2 ah = __builtin_bit_cast(h16x2, aw[j]);
                    x0 = __builtin_amdgcn_fdot2(ah, wx[j], x0, false);
                    x1 = __builtin_amdgcn_fdot2(ah, wy[j], x1, false);
                }
                acc0 += silu_f(x0);
                acc1 += silu_f(x1);
            }
            if (base + (uint32_t)i2 == eend) {
                // finalize current edge (and any empty-edge chain)
                do {
                    float2 o;
                    o.x = acc0;
                    o.y = acc1;
                    ((float2*)S)[(size_t)ecur * 64 + lane] = o;
                    acc0 = 0.f;
                    acc1 = 0.f;
                    ++ecur;
                    if (ecur >= ee) { eend = 0xffffffffu; break; }
                    p1A = p1B;
                    p1B = Ppk[(size_t)min(ecur + 1, E - 1) * 128 + lane];
                    p1lo = bf_lo(p1A) + b1v.x;
                    p1hi = bf_hi(p1A) + b1v.y;
                    eend = __shfl(offv, ecur - eb + 1);
                } while (base + (uint32_t)i2 == eend);
            }
        }
    }
    // flush (covers all-empty waves; normally a no-op)
    while (ecur < ee) {
        float2 o;
        o.x = acc0;
        o.y = acc1;
        ((float2*)S)[(size_t)ecur * 64 + lane] = o;
        acc0 = 0.f;
        acc1 = 0.f;
        ++ecur;
    }
}

// ---------------------------------------------------------------------------
// kC2: MFMA out = S @ M + cnt*cvec + bu, in-place. Block: 64 rows x 128 cols.
// ---------------------------------------------------------------------------
__global__ void __launch_bounds__(256) kC2(const float* __restrict__ S,
                                           const uint32_t* __restrict__ Mfrag,
                                           const float* __restrict__ cvec,
                                           const float* __restrict__ bu,
                                           const uint32_t* __restrict__ cnt,
                                           int E) {
    __shared__ uint32_t As[4096];    // 64 x 64 dwords swizzled (16KB)
    __shared__ uint32_t Bs[8192];    // 32KB fragment-ordered M
    __shared__ float cnt_s[64];
    const int tid = threadIdx.x;
    const int e0 = blockIdx.x * 64;
    const int nE = min(64, E - e0);

    for (int d = tid; d < 4096; d += 256) {
        int row = d >> 6, p = d & 63;
        int g = p >> 2;
        float2 v;
        if (row < nE) v = *(const float2*)(S + (size_t)(e0 + row) * 128 + 2 * p);
        else { v.x = 0.f; v.y = 0.f; }
        As[row * 64 + ((g ^ (row & 7)) << 2) + (p & 3)] = pack_bf2(v.x, v.y);
    }
    for (int d = tid; d < 2048; d += 256)
        ((uint4*)Bs)[d] = ((const uint4*)Mfrag)[d];
    if (tid < 64) cnt_s[tid] = (tid < nE) ? (float)cnt[e0 + tid] : 0.f;
    __syncthreads();

    const int w = tid >> 6, l = tid & 63;

    bf16x8 afr[4][4];
#pragma unroll
    for (int rb = 0; rb < 4; ++rb)
#pragma unroll
        for (int s = 0; s < 4; ++s) {
            int row = rb * 16 + (l & 15);
            int g = s * 4 + (l >> 4);
            afr[rb][s] = *(const bf16x8*)((const char*)As + row * 256 + ((g ^ (row & 7)) << 4));
        }

    f32x4 acc[2][4];
#pragma unroll
    for (int cl = 0; cl < 2; ++cl)
#pragma unroll
        for (int rb = 0; rb < 4; ++rb) acc[cl][rb] = (f32x4)(0.f);

#pragma unroll
    for (int cl = 0; cl < 2; ++cl) {
        const int c = w * 2 + cl;
#pragma unroll
        for (int s = 0; s < 4; ++s) {
            bf16x8 bfr = *(const bf16x8*)((const char*)Bs + (((s * 8 + c) * 64 + l) << 4));
#pragma unroll
            for (int rb = 0; rb < 4; ++rb)
                acc[cl][rb] = __builtin_amdgcn_mfma_f32_16x16x32_bf16(afr[rb][s], bfr, acc[cl][rb], 0, 0, 0);
        }
    }

    // epilogue: + cnt*cvec + bu, write fp32 in place
#pragma unroll
    for (int cl = 0; cl < 2; ++cl) {
        const int col = w * 32 + cl * 16 + (l & 15);
        const float cv = cvec[col];
        const float bv = bu[col];
#pragma unroll
        for (int rb = 0; rb < 4; ++rb)
#pragma unroll
            for (int r = 0; r < 4; ++r) {
                int row = rb * 16 + (l >> 4) * 4 + r;
                if (row < nE) {
                    float* dst = (float*)S + (size_t)(e0 + row) * 128 + col;
                    *dst = acc[cl][rb][r] + fmaf(cnt_s[row], cv, bv);
                }
            }
    }
}

// ---------------------------------------------------------------------------
extern "C" void kernel_launch(void* const* d_in, const int* in_sizes, int n_in,
                              void* d_out, int out_size, void* d_ws, size_t ws_size,
                              hipStream_t stream) {
    const float* edge_attr = (const float*)d_in[0];
    // d_in[1]: three_body_indices — unused by the reference computation
    const int* tbe = (const int*)d_in[2];
    const float* evec = (const float*)d_in[3];
    const float* Wa1 = (const float*)d_in[4];
    const float* ba1 = (const float*)d_in[5];
    const float* Wa2 = (const float*)d_in[6];
    const float* ba2 = (const float*)d_in[7];
    const float* W1 = (const float*)d_in[8];
    const float* b1 = (const float*)d_in[9];
    const float* W2 = (const float*)d_in[10];
    const float* b2 = (const float*)d_in[11];
    const float* Wu = (const float*)d_in[12];
    const float* bu = (const float*)d_in[13];

    const int E = in_sizes[0] / 128;
    const int T = in_sizes[2] / 2;
    float* S = (float*)d_out;

    const int nScanBlk = (E + 255) / 256;

    char* ws = (char*)d_ws;
    size_t off = 0;
    uint32_t* Ppk = (uint32_t*)(ws + off); off += (size_t)E * 512;           // bf16 E x 256
    uint32_t* cnt = (uint32_t*)(ws + off); off += (size_t)E * 4;
    uint32_t* offs = (uint32_t*)(ws + off); off += (size_t)E * 4;
    uint32_t* sortedE2 = (uint32_t*)(ws + off); off += ((size_t)T + 64) * 4;  // +64 pad
    uint32_t* afpk = (uint32_t*)(ws + off); off += ((size_t)T + 64) * 40;     // +64-row pad
    uint32_t* bsum = (uint32_t*)(ws + off); off += (size_t)((nScanBlk + 3) & ~3) * 4;
    uint32_t* Bpk = (uint32_t*)(ws + off); off += 65536;
    uint32_t* W1cf16 = (uint32_t*)(ws + off); off += 8192;
    uint32_t* Mfrag = (uint32_t*)(ws + off); off += 32768;
    float* cvec = (float*)(ws + off); off += 512;

    hipMemsetAsync(cnt, 0, (size_t)E * 4, stream);

    prepA<<<130, 256, 0, stream>>>(W2, b2, Wu, W1, cvec, Bpk, W1cf16, Mfrag);
    kA3<<<(E + 63) / 64, 256, 0, stream>>>(edge_attr, Bpk, (uint16_t*)Ppk, E);
    khist<<<1024, 256, 0, stream>>>(tbe, cnt, T);
    scanA<<<nScanBlk, 256, 0, stream>>>(cnt, bsum, E);
    scanB<<<1, 512, 0, stream>>>(bsum, nScanBlk);
    scanC<<<nScanBlk, 256, 0, stream>>>(cnt, bsum, offs, E);
    kSA<<<(T + 255) / 256, 256, 0, stream>>>(tbe, evec, Wa1, ba1, Wa2, ba2,
                                             offs, afpk, sortedE2, T);
    const int nWaves = (E + EG - 1) / EG;
    kB8<<<(nWaves + 3) / 4, 256, 0, stream>>>(sortedE2, offs, W1cf16, b1, Ppk, afpk, S, E);
    kC2<<<(E + 63) / 64, 256, 0, stream>>>(S, Mfrag, cvec, bu, cnt, E);
}